// Round 23
// baseline (434.635 us; speedup 1.0000x reference)
//
#include <hip/hip_runtime.h>

#define DIM 128
#define NLEV 8
#define NB_STAGE 512           // stage-kernel grid; 4 waves/block -> 2048 wave-slots
#define NSLOT (NB_STAGE * 4)
#define CAP NSLOT              // max nodes per class (expected ~1213, +24 sigma)

// packed stage-weight offsets (float4 units): slot (k>>1)*64+jl holds
// (W[k][jl], W[k][jl+64], W[k+1][jl], W[k+1][jl+64])
#define AS4 0
#define UA4 4096               // 256 rows -> 8192 float4
#define NS4 12288
#define UN4 16384
#define PACK4_TOTAL 20480
#define DEC_TOTAL 16384        // float2: (dec_ws[k][j], dec_wt[k][j])

__device__ __forceinline__ int cls_of(int g, int l) {
    if (l < 1 || l > NLEV) return -1;
    if (g == 1) return l - 1;
    if (g == 2) return NLEV + (l - 1);
    return -1;
}

// ---------------- prep kernels ----------------

// fused: deg_count (i<E) + class-list build (blocks covering n)
__global__ __launch_bounds__(256) void count_kernel(const int* __restrict__ dstv,
                                                    int* __restrict__ degi, int E,
                                                    const int* __restrict__ gate,
                                                    const int* __restrict__ level,
                                                    int* __restrict__ nlist,
                                                    int* __restrict__ ncnt,
                                                    int* __restrict__ clsidx, int n) {
    const int i = blockIdx.x * 256 + threadIdx.x;
    if (i < E) atomicAdd(&degi[dstv[i]], 1);
    if ((int)blockIdx.x * 256 < n) {  // block-uniform
        __shared__ int lcnt[16];
        __shared__ int lbase[16];
        const int t = threadIdx.x;
        if (t < 16) lcnt[t] = 0;
        __syncthreads();
        int c = -1, lpos = 0;
        if (i < n) {
            c = cls_of(gate[i], level[i]);
            if (c >= 0) lpos = atomicAdd(&lcnt[c], 1);
        }
        __syncthreads();
        if (t < 16 && lcnt[t] > 0) lbase[t] = atomicAdd(&ncnt[t], lcnt[t]);
        __syncthreads();
        if (c >= 0) {
            int idx = lbase[c] + lpos;
            nlist[c * n + idx] = i;
            clsidx[i] = (c << 16) | idx;
        }
    }
}

// pack stage weights (float4 k-pair layout), decoder weights (float2), b' tail
__global__ void pack_kernel(const float* __restrict__ as_w, const float* __restrict__ ua_w,
                            const float* __restrict__ ns_w, const float* __restrict__ un_w,
                            float4* __restrict__ wp4,
                            const float* __restrict__ ws_w, const float* __restrict__ wt_w,
                            float2* __restrict__ wdec,
                            const float* __restrict__ gcn_b, const float* __restrict__ mu_w,
                            const float* __restrict__ mu_b, float* __restrict__ bp) {
    if (blockIdx.x == gridDim.x - 1) {  // bprime tail block
        const int j = threadIdx.x;
        if (j < DIM) {
            float acc = mu_b[j];
            for (int k = 0; k < DIM; k++) acc = fmaf(gcn_b[k], mu_w[k * DIM + j], acc);
            bp[j] = acc;
        }
        return;
    }
    const int i = blockIdx.x * 256 + threadIdx.x;
    if (i < PACK4_TOTAL) {
        const float* src;
        int local;
        if (i < UA4)      { src = as_w; local = i; }
        else if (i < NS4) { src = ua_w; local = i - UA4; }
        else if (i < UN4) { src = ns_w; local = i - NS4; }
        else              { src = un_w; local = i - UN4; }
        const int kp = local >> 6, jl = local & 63;
        wp4[i] = make_float4(src[(2 * kp) * DIM + jl], src[(2 * kp) * DIM + jl + 64],
                             src[(2 * kp + 1) * DIM + jl], src[(2 * kp + 1) * DIM + jl + 64]);
    } else if (i < PACK4_TOTAL + DEC_TOTAL) {
        const int d = i - PACK4_TOTAL;
        wdec[d] = make_float2(ws_w[d], wt_w[d]);  // d = k*DIM + j
    }
}

// ---- 2-kernel parallel exclusive scan (+ fused deg finalize) ----
__global__ __launch_bounds__(1024) void scan1_kernel(const int* __restrict__ degi,
                                                     int* __restrict__ offs,
                                                     int* __restrict__ bsum,
                                                     float* __restrict__ dis,
                                                     float* __restrict__ inv) {
    __shared__ int sh[1024];
    const int gid = blockIdx.x * 1024 + threadIdx.x;
    const int v = degi[gid];
    {
        float d = (float)v + 1.0f;
        dis[gid] = rsqrtf(d);
        inv[gid] = 1.0f / d;
    }
    sh[threadIdx.x] = v;
    __syncthreads();
    for (int off = 1; off < 1024; off <<= 1) {
        int t = (threadIdx.x >= off) ? sh[threadIdx.x - off] : 0;
        __syncthreads();
        sh[threadIdx.x] += t;
        __syncthreads();
    }
    offs[gid] = sh[threadIdx.x] - v;  // exclusive within block
    if (threadIdx.x == 1023) bsum[blockIdx.x] = sh[1023];
}

// scan3 with local re-scan of bsum (scan2 merged; bsum read-only here)
__global__ __launch_bounds__(1024) void scan3_kernel(int* __restrict__ offs,
                                                     const int* __restrict__ bsum, int n) {
    __shared__ int sbase, stot;
    const int nb = gridDim.x;
    if (threadIdx.x < 64) {
        const int lane = threadIdx.x;
        const int orig = (lane < nb) ? bsum[lane] : 0;
        int v = orig;
#pragma unroll
        for (int off = 1; off < 64; off <<= 1) {
            int t = __shfl_up(v, off, 64);
            if (lane >= off) v += t;
        }
        if (lane == (int)blockIdx.x) sbase = v - orig;  // exclusive base for this block
        if (lane == nb - 1) stot = v;                   // grand total
    }
    __syncthreads();
    const int gid = blockIdx.x * 1024 + threadIdx.x;
    offs[gid] += sbase;
    if (gid == n - 1) offs[n] = stot;
}

__global__ void csr_fill_kernel(const int* __restrict__ srcv, const int* __restrict__ dstv,
                                const int* __restrict__ offs, int* __restrict__ cursor,
                                int* __restrict__ csr_src, int E) {
    int i = blockIdx.x * blockDim.x + threadIdx.x;
    if (i >= E) return;
    int d = dstv[i];
    int pos = offs[d] + atomicAdd(&cursor[d], 1);
    csr_src[pos] = srcv[i];
}

// per-class packed node metadata: meta[c*CAP+idx] = (node, e0, e1, 0)
__global__ __launch_bounds__(256) void meta_kernel(const int* __restrict__ nlist,
                                                   const int* __restrict__ ncnt,
                                                   const int* __restrict__ offs,
                                                   int4* __restrict__ meta, int n) {
    const int c = blockIdx.x >> 3;              // 8 blocks per class (CAP/256)
    const int idx = (blockIdx.x & 7) * 256 + threadIdx.x;
    if (idx >= min(ncnt[c], CAP)) return;
    const int node = nlist[c * n + idx];
    meta[c * CAP + idx] = make_int4(node, offs[node], offs[node + 1], 0);
}

// ---------------- dense matmul: LDS-staged input tile, 32 rows/block ----------------
template <int BIAS>
__global__ __launch_bounds__(256) void mm_kernel(const float* __restrict__ in0,
                                                 const float* __restrict__ W,
                                                 const float* __restrict__ b,
                                                 float* __restrict__ out, int n) {
    const int R = 32;
    __shared__ float tile[R * DIM];
    const size_t row0 = (size_t)blockIdx.x * R;
    for (int t = threadIdx.x; t < R * DIM / 4; t += 256)
        ((float4*)tile)[t] = ((const float4*)(in0 + row0 * DIM))[t];
    __syncthreads();
    const int g = threadIdx.x >> 7;   // row-half 0/1
    const int j = threadIdx.x & 127;  // output column
    float acc[16];
#pragma unroll
    for (int r = 0; r < 16; r++) acc[r] = 0.f;
    const float* tb = tile + (g * 16) * DIM;
    for (int k = 0; k < DIM; k += 4) {
        float w0 = W[(k + 0) * DIM + j];
        float w1 = W[(k + 1) * DIM + j];
        float w2 = W[(k + 2) * DIM + j];
        float w3 = W[(k + 3) * DIM + j];
#pragma unroll
        for (int r = 0; r < 16; r++) {
            const float4 a = *reinterpret_cast<const float4*>(tb + r * DIM + k);
            acc[r] = fmaf(a.x, w0, acc[r]);
            acc[r] = fmaf(a.y, w1, acc[r]);
            acc[r] = fmaf(a.z, w2, acc[r]);
            acc[r] = fmaf(a.w, w3, acc[r]);
        }
    }
    float bias = BIAS ? b[j] : 0.f;
#pragma unroll
    for (int r = 0; r < 16; r++) out[(row0 + g * 16 + r) * DIM + j] = acc[r] + bias;
}

// uH precompute: for all AND classes c in [0,8): uH[c*CAP+idx] = hs[node] @ ua_w[0:128] + ua_b
// (valid because AND-node hs rows hold the encoder value until their own level's commit)
__global__ __launch_bounds__(256) void uh_kernel(const float* __restrict__ hs,
                                                 const float* __restrict__ ua_w,
                                                 const float* __restrict__ ua_b,
                                                 const int* __restrict__ nlist,
                                                 const int* __restrict__ ncnt,
                                                 float* __restrict__ uH, int n) {
    const int c = blockIdx.x >> 6;          // 64 blocks per class, 32 rows each -> CAP rows
    const int i0 = (blockIdx.x & 63) * 32;
    const int cnt = min(ncnt[c], CAP);
    if (i0 >= cnt) return;
    __shared__ float tile[32 * DIM];
    {   // gather-stage 32 node rows (8 threads/row, 4 float4 each)
        const int rt = threadIdx.x >> 3;
        const int ct = threadIdx.x & 7;
        const int idx = min(i0 + rt, cnt - 1);
        const int node = nlist[c * n + idx];
        const float4* s4 = (const float4*)(hs + (size_t)node * DIM);
        float4* d4 = (float4*)(tile + rt * DIM);
#pragma unroll
        for (int i = 0; i < 4; i++) d4[ct + 8 * i] = s4[ct + 8 * i];
    }
    __syncthreads();
    const int g = threadIdx.x >> 7;
    const int j = threadIdx.x & 127;
    float acc[16];
#pragma unroll
    for (int r = 0; r < 16; r++) acc[r] = 0.f;
    const float* tb = tile + (g * 16) * DIM;
    float w0 = ua_w[0 * DIM + j], w1 = ua_w[1 * DIM + j];
    float w2 = ua_w[2 * DIM + j], w3 = ua_w[3 * DIM + j];
    for (int k = 0; k < DIM; k += 4) {
        const int kn = (k + 4 < DIM) ? (k + 4) : 0;
        const float nw0 = ua_w[(kn + 0) * DIM + j];
        const float nw1 = ua_w[(kn + 1) * DIM + j];
        const float nw2 = ua_w[(kn + 2) * DIM + j];
        const float nw3 = ua_w[(kn + 3) * DIM + j];
#pragma unroll
        for (int r = 0; r < 16; r++) {
            const float4 a = *reinterpret_cast<const float4*>(tb + r * DIM + k);
            acc[r] = fmaf(a.x, w0, acc[r]);
            acc[r] = fmaf(a.y, w1, acc[r]);
            acc[r] = fmaf(a.z, w2, acc[r]);
            acc[r] = fmaf(a.w, w3, acc[r]);
        }
        w0 = nw0; w1 = nw1; w2 = nw2; w3 = nw3;
    }
    const float bj = ua_b[j];
#pragma unroll
    for (int r = 0; r < 16; r++) {
        const int idx = i0 + g * 16 + r;
        if (idx < cnt) uH[((size_t)c * CAP + idx) * DIM + j] = acc[r] + bj;
    }
}

// fused decoder matmul: packed (ws,wt) float2 per k, depth-2 prefetch (round-18 proven)
__global__ __launch_bounds__(256) void mm2_kernel(const float* __restrict__ in0,
                                                  const float2* __restrict__ Wd,
                                                  float* __restrict__ zs,
                                                  float* __restrict__ zt, int n) {
    const int R = 32;
    __shared__ float tile[R * DIM];
    const size_t row0 = (size_t)blockIdx.x * R;
    for (int t = threadIdx.x; t < R * DIM / 4; t += 256)
        ((float4*)tile)[t] = ((const float4*)(in0 + row0 * DIM))[t];
    __syncthreads();
    const int g = threadIdx.x >> 7;
    const int j = threadIdx.x & 127;
    float accs[16], acct[16];
#pragma unroll
    for (int r = 0; r < 16; r++) { accs[r] = 0.f; acct[r] = 0.f; }
    const float* tb = tile + (g * 16) * DIM;
    float2 s0 = Wd[0 * DIM + j], s1 = Wd[1 * DIM + j];
    float2 s2 = Wd[2 * DIM + j], s3 = Wd[3 * DIM + j];
    for (int k = 0; k < DIM; k += 2) {
        const int kn = (k + 4 < DIM) ? (k + 4) : 0;  // depth-2 prefetch
        const float2 p0 = Wd[(kn + 0) * DIM + j];
        const float2 p1 = Wd[(kn + 1) * DIM + j];
#pragma unroll
        for (int r = 0; r < 16; r++) {
            const float2 a = *reinterpret_cast<const float2*>(tb + r * DIM + k);
            accs[r] = fmaf(a.x, s0.x, accs[r]);
            acct[r] = fmaf(a.x, s0.y, acct[r]);
            accs[r] = fmaf(a.y, s1.x, accs[r]);
            acct[r] = fmaf(a.y, s1.y, acct[r]);
        }
        s0 = s2; s1 = s3; s2 = p0; s3 = p1;
    }
#pragma unroll
    for (int r = 0; r < 16; r++) {
        zs[(row0 + g * 16 + r) * DIM + j] = accs[r];
        zt[(row0 + g * 16 + r) * DIM + j] = acct[r];
    }
}

// ---------------- GCN aggregate as gather (bias folded into b'; 2-edge unroll) ----------------
__global__ __launch_bounds__(256) void gcn_gather_kernel(const float* __restrict__ x,
                                                         const float* __restrict__ dis,
                                                         const float* __restrict__ inv,
                                                         const int* __restrict__ offs,
                                                         const int* __restrict__ csr_src,
                                                         float* __restrict__ y, int n) {
    int slot = threadIdx.x >> 7, j = threadIdx.x & 127;
    for (int node = blockIdx.x * 2 + slot; node < n; node += gridDim.x * 2) {
        float dn = dis[node];
        float acc = inv[node] * x[(size_t)node * DIM + j];
        const int p0 = offs[node], p1 = offs[node + 1];
        for (int p = p0; p < p1; p += 2) {
            const bool two = (p + 1 < p1);
            const int s0 = csr_src[p];
            const int s1 = two ? csr_src[p + 1] : s0;
            const float c0 = dn * dis[s0];
            const float c1 = dn * dis[s1];
            const float v0 = x[(size_t)s0 * DIM + j];
            const float v1 = x[(size_t)s1 * DIM + j];
            acc = fmaf(c0, v0, acc);
            if (two) acc = fmaf(c1, v1, acc);
        }
        y[(size_t)node * DIM + j] = acc;
    }
}

// ---------------- level-stage kernels: wave-per-node, ALL W direct from L2 ----------------

template <bool MERGE>
__device__ __forceinline__ const float* resolve_row(const float* __restrict__ base,
                                                    const float* __restrict__ tmp,
                                                    const int* __restrict__ clsidx,
                                                    int mcls, int s) {
    if (MERGE) {
        int cc = clsidx[s];
        if ((cc >> 16) == mcls && (cc & 0xFFFF) < CAP) return tmp + (size_t)(cc & 0xFFFF) * DIM;
    }
    return base + (size_t)s * DIM;
}

// load one edge pair's src rows into registers (global; issued early for latency hiding)
template <bool MERGE>
__device__ __forceinline__ void load_pair(const float* __restrict__ hs,
                                          const float* __restrict__ tmp,
                                          const int* __restrict__ clsidx, int mcls,
                                          const int* __restrict__ csr_src,
                                          int p, int e1, int lane,
                                          float& a00, float& a01, float& a10, float& a11) {
    const int s0 = csr_src[p];
    const int s1 = (p + 1 < e1) ? csr_src[p + 1] : s0;
    const float* r0 = resolve_row<MERGE>(hs, tmp, clsidx, mcls, s0);
    const float* r1 = resolve_row<MERGE>(hs, tmp, clsidx, mcls, s1);
    a00 = r0[lane]; a01 = r0[lane + 64];
    a10 = r1[lane]; a11 = r1[lane + 64];
}

// 128-step matvec col-pair accumulation from per-wave LDS row `ar`, W read directly
// from L2 (fully coalesced float4 per lane; single pass -> latency amortized)
__device__ __forceinline__ void mv128_l2(const float* __restrict__ ar,
                                         const float4* __restrict__ Wg,
                                         int lane, float& o0, float& o1) {
#pragma unroll 8
    for (int k = 0; k < 128; k += 4) {
        const float4 a = *(const float4*)&ar[k];  // uniform-address LDS broadcast
        const float4 wA = Wg[(k >> 1) * 64 + lane];        // rows k, k+1
        const float4 wB = Wg[((k >> 1) + 1) * 64 + lane];  // rows k+2, k+3
        o0 = fmaf(a.x, wA.x, o0); o1 = fmaf(a.x, wA.y, o1);
        o0 = fmaf(a.y, wA.z, o0); o1 = fmaf(a.y, wA.w, o1);
        o0 = fmaf(a.z, wB.x, o0); o1 = fmaf(a.z, wB.y, o1);
        o0 = fmaf(a.w, wB.z, o0); o1 = fmaf(a.w, wB.w, o1);
    }
}

// AND stage: commit tmpN(cNp)->hs ; agg = gather(as_w L2, merged w/ tmpN) ;
//            tmpA[idx] = relu( uH[idx] + agg @ ua_w[128:256] (L2) )
// Zero block-level synchronization: no LDS W staging, arow is per-wave.
template <bool MERGE>
__global__ __launch_bounds__(256) void and_stage_kernel(
        float* __restrict__ hs, const float* __restrict__ tmpN, float* __restrict__ tmpA,
        const int4* __restrict__ meta, const int* __restrict__ csr_src,
        const int* __restrict__ ncnt, const int* __restrict__ clsidx,
        const float4* __restrict__ wp4,
        const float* __restrict__ as_b, const float* __restrict__ uH,
        int cA, int cNp, int n) {
    const int cnt = min(ncnt[cA], CAP);
    const int cntp = MERGE ? min(ncnt[cNp], CAP) : 0;
    const int lim = max(cnt, cntp);
    if ((int)blockIdx.x * 4 >= lim) return;  // block-uniform early exit
    __shared__ float arow[4][256];  // per-wave row scratch (2 rows of 128)
    const int lane = threadIdx.x & 63;
    const int wv = threadIdx.x >> 6;
    const int gslot = (blockIdx.x << 2) | wv;

    const bool act = gslot < cnt;
    const int4 mt = act ? meta[cA * CAP + gslot] : make_int4(0, 0, 0, 0);
    const int e0 = mt.y, e1 = mt.z;
    float u0 = 0.f, u1 = 0.f;
    if (act) {  // precomputed hs-half of update (includes ua_b)
        u0 = uH[((size_t)cA * CAP + gslot) * DIM + lane];
        u1 = uH[((size_t)cA * CAP + gslot) * DIM + lane + 64];
    }
    float pa0 = 0.f, pa1 = 0.f, pa2 = 0.f, pa3 = 0.f;
    if (act && e0 < e1)
        load_pair<MERGE>(hs, tmpN, clsidx, cNp, csr_src, e0, e1, lane, pa0, pa1, pa2, pa3);
    // commit previous level's NOT updates (gathers read those rows via tmpN indirection)
    if (MERGE) {
        for (int idx = gslot; idx < cntp; idx += NSLOT) {
            const int node = meta[cNp * CAP + idx].x;
            hs[(size_t)node * DIM + lane] = tmpN[(size_t)idx * DIM + lane];
            hs[(size_t)node * DIM + lane + 64] = tmpN[(size_t)idx * DIM + lane + 64];
        }
    }

    // ---- gather: software-pipelined edge pairs, W direct from L2 ----
    const float4* Was = wp4 + AS4;
    const float bj_as0 = as_b[lane], bj_as1 = as_b[lane + 64];
    float ag0 = 0.f, ag1 = 0.f;
    if (act) {
        float* ar = arow[wv];
        float a00 = pa0, a01 = pa1, a10 = pa2, a11 = pa3;
        for (int p = e0; p < e1; p += 2) {
            ar[lane] = a00; ar[64 + lane] = a01;
            ar[128 + lane] = a10; ar[192 + lane] = a11;
            const bool two = (p + 1 < e1);
            float n00 = 0.f, n01 = 0.f, n10 = 0.f, n11 = 0.f;
            if (p + 2 < e1)  // prefetch next pair during this pair's k-loop
                load_pair<MERGE>(hs, tmpN, clsidx, cNp, csr_src, p + 2, e1, lane,
                                 n00, n01, n10, n11);
            float m00 = bj_as0, m01 = bj_as1, m10 = bj_as0, m11 = bj_as1;
#pragma unroll 8
            for (int k = 0; k < 128; k += 4) {
                const float4 a0 = *(const float4*)&ar[k];
                const float4 a1 = *(const float4*)&ar[128 + k];
                const float4 wA = Was[(k >> 1) * 64 + lane];
                const float4 wB = Was[((k >> 1) + 1) * 64 + lane];
                m00 = fmaf(a0.x, wA.x, m00); m01 = fmaf(a0.x, wA.y, m01);
                m10 = fmaf(a1.x, wA.x, m10); m11 = fmaf(a1.x, wA.y, m11);
                m00 = fmaf(a0.y, wA.z, m00); m01 = fmaf(a0.y, wA.w, m01);
                m10 = fmaf(a1.y, wA.z, m10); m11 = fmaf(a1.y, wA.w, m11);
                m00 = fmaf(a0.z, wB.x, m00); m01 = fmaf(a0.z, wB.y, m01);
                m10 = fmaf(a1.z, wB.x, m10); m11 = fmaf(a1.z, wB.y, m11);
                m00 = fmaf(a0.w, wB.z, m00); m01 = fmaf(a0.w, wB.w, m01);
                m10 = fmaf(a1.w, wB.z, m10); m11 = fmaf(a1.w, wB.w, m11);
            }
            ag0 += fmaxf(m00, 0.f);
            ag1 += fmaxf(m01, 0.f);
            if (two) { ag0 += fmaxf(m10, 0.f); ag1 += fmaxf(m11, 0.f); }
            a00 = n00; a01 = n01; a10 = n10; a11 = n11;
        }
        // ---- update: u = uH + agg @ ua_w[128:256] (L2); no barrier ----
        float* ar2 = arow[wv];
        ar2[lane] = ag0; ar2[64 + lane] = ag1;
        mv128_l2(ar2, wp4 + UA4 + 4096, lane, u0, u1);
        tmpA[(size_t)gslot * DIM + lane] = fmaxf(u0, 0.f);
        tmpA[(size_t)gslot * DIM + lane + 64] = fmaxf(u1, 0.f);
    }
}

// NOT stage: commit tmpA(cA)->hs ; agg = gather(ns_w L2, merged w/ tmpA) ;
//            tmpN[idx] = tanh( agg @ un_w (L2) + un_b )
__global__ __launch_bounds__(256) void not_stage_kernel(
        float* __restrict__ hs, const float* __restrict__ tmpA, float* __restrict__ tmpN,
        const int4* __restrict__ meta, const int* __restrict__ csr_src,
        const int* __restrict__ ncnt, const int* __restrict__ clsidx,
        const float4* __restrict__ wp4,
        const float* __restrict__ ns_b, const float* __restrict__ un_b,
        int cA, int cN, int n) {
    const int cnt = min(ncnt[cN], CAP);
    const int cntA = min(ncnt[cA], CAP);
    const int lim = max(cnt, cntA);
    if ((int)blockIdx.x * 4 >= lim) return;
    __shared__ float arow[4][256];
    const int lane = threadIdx.x & 63;
    const int wv = threadIdx.x >> 6;
    const int gslot = (blockIdx.x << 2) | wv;

    const bool act = gslot < cnt;
    const int4 mt = act ? meta[cN * CAP + gslot] : make_int4(0, 0, 0, 0);
    const int e0 = mt.y, e1 = mt.z;
    float pa0 = 0.f, pa1 = 0.f, pa2 = 0.f, pa3 = 0.f;
    if (act && e0 < e1)
        load_pair<true>(hs, tmpA, clsidx, cA, csr_src, e0, e1, lane, pa0, pa1, pa2, pa3);
    // commit this level's AND updates
    for (int idx = gslot; idx < cntA; idx += NSLOT) {
        const int node = meta[cA * CAP + idx].x;
        hs[(size_t)node * DIM + lane] = tmpA[(size_t)idx * DIM + lane];
        hs[(size_t)node * DIM + lane + 64] = tmpA[(size_t)idx * DIM + lane + 64];
    }

    const float4* Wns = wp4 + NS4;
    const float bj_ns0 = ns_b[lane], bj_ns1 = ns_b[lane + 64];
    float ag0 = 0.f, ag1 = 0.f;
    if (act) {
        float* ar = arow[wv];
        float a00 = pa0, a01 = pa1, a10 = pa2, a11 = pa3;
        for (int p = e0; p < e1; p += 2) {
            ar[lane] = a00; ar[64 + lane] = a01;
            ar[128 + lane] = a10; ar[192 + lane] = a11;
            const bool two = (p + 1 < e1);
            float n00 = 0.f, n01 = 0.f, n10 = 0.f, n11 = 0.f;
            if (p + 2 < e1)
                load_pair<true>(hs, tmpA, clsidx, cA, csr_src, p + 2, e1, lane,
                                n00, n01, n10, n11);
            float m00 = bj_ns0, m01 = bj_ns1, m10 = bj_ns0, m11 = bj_ns1;
#pragma unroll 8
            for (int k = 0; k < 128; k += 4) {
                const float4 a0 = *(const float4*)&ar[k];
                const float4 a1 = *(const float4*)&ar[128 + k];
                const float4 wA = Wns[(k >> 1) * 64 + lane];
                const float4 wB = Wns[((k >> 1) + 1) * 64 + lane];
                m00 = fmaf(a0.x, wA.x, m00); m01 = fmaf(a0.x, wA.y, m01);
                m10 = fmaf(a1.x, wA.x, m10); m11 = fmaf(a1.x, wA.y, m11);
                m00 = fmaf(a0.y, wA.z, m00); m01 = fmaf(a0.y, wA.w, m01);
                m10 = fmaf(a1.y, wA.z, m10); m11 = fmaf(a1.y, wA.w, m11);
                m00 = fmaf(a0.z, wB.x, m00); m01 = fmaf(a0.z, wB.y, m01);
                m10 = fmaf(a1.z, wB.x, m10); m11 = fmaf(a1.z, wB.y, m11);
                m00 = fmaf(a0.w, wB.z, m00); m01 = fmaf(a0.w, wB.w, m01);
                m10 = fmaf(a1.w, wB.z, m10); m11 = fmaf(a1.w, wB.w, m11);
            }
            ag0 += fmaxf(m00, 0.f);
            ag1 += fmaxf(m01, 0.f);
            if (two) { ag0 += fmaxf(m10, 0.f); ag1 += fmaxf(m11, 0.f); }
            a00 = n00; a01 = n01; a10 = n10; a11 = n11;
        }
        // ---- update from L2 W; no barriers ----
        float u0 = un_b[lane], u1 = un_b[lane + 64];
        float* ar2 = arow[wv];
        ar2[lane] = ag0; ar2[64 + lane] = ag1;
        mv128_l2(ar2, wp4 + UN4, lane, u0, u1);
        tmpN[(size_t)gslot * DIM + lane] = tanhf(u0);
        tmpN[(size_t)gslot * DIM + lane + 64] = tanhf(u1);
    }
}

// final commit of last level's tmpN -> hs
__global__ __launch_bounds__(256) void commit_kernel(float* __restrict__ hs,
                                                     const float* __restrict__ tmp,
                                                     const int4* __restrict__ meta,
                                                     const int* __restrict__ ncnt,
                                                     int c, int n) {
    const int lane = threadIdx.x & 63;
    const int gslot = (blockIdx.x << 2) | (threadIdx.x >> 6);
    const int cnt = min(ncnt[c], CAP);
    for (int idx = gslot; idx < cnt; idx += NSLOT) {
        const int node = meta[c * CAP + idx].x;
        hs[(size_t)node * DIM + lane] = tmp[(size_t)idx * DIM + lane];
        hs[(size_t)node * DIM + lane + 64] = tmp[(size_t)idx * DIM + lane + 64];
    }
}

// ---------------- decoder as gather (wave per node, 2-edge unroll) ----------------
__global__ __launch_bounds__(256) void dec_gather_kernel(const float* __restrict__ zs,
                                                         const float* __restrict__ zt,
                                                         const int* __restrict__ offs,
                                                         const int* __restrict__ csr_src,
                                                         float* __restrict__ hf_out, int n) {
    int w = threadIdx.x >> 6, lane = threadIdx.x & 63;
    for (int node = blockIdx.x * 4 + w; node < n; node += gridDim.x * 4) {
        float b0 = zt[(size_t)node * DIM + lane];
        float b1 = zt[(size_t)node * DIM + 64 + lane];
        float acc0 = 0.f, acc1 = 0.f;
        const int p0 = offs[node], p1 = offs[node + 1];
        for (int p = p0; p < p1; p += 2) {
            const bool two = (p + 1 < p1);
            const int s0 = csr_src[p];
            const int s1 = two ? csr_src[p + 1] : s0;
            const float a00 = zs[(size_t)s0 * DIM + lane];
            const float a01 = zs[(size_t)s0 * DIM + 64 + lane];
            const float a10 = zs[(size_t)s1 * DIM + lane];
            const float a11 = zs[(size_t)s1 * DIM + 64 + lane];
            float pd0 = a00 * b0 + a01 * b1;
            float pd1 = a10 * b0 + a11 * b1;
#pragma unroll
            for (int off = 32; off > 0; off >>= 1) {
                pd0 += __shfl_xor(pd0, off, 64);
                pd1 += __shfl_xor(pd1, off, 64);
            }
            const float w0 = 1.f / (1.f + __expf(-pd0));
            acc0 = fmaf(w0, a00, acc0);
            acc1 = fmaf(w0, a01, acc1);
            if (two) {
                const float w1 = 1.f / (1.f + __expf(-pd1));
                acc0 = fmaf(w1, a10, acc0);
                acc1 = fmaf(w1, a11, acc1);
            }
        }
        hf_out[(size_t)node * DIM + lane] = acc0;
        hf_out[(size_t)node * DIM + 64 + lane] = acc1;
    }
}

extern "C" void kernel_launch(void* const* d_in, const int* in_sizes, int n_in,
                              void* d_out, int out_size, void* d_ws, size_t ws_size,
                              hipStream_t stream) {
    const float* hs_init = (const float*)d_in[0];
    const int* ei = (const int*)d_in[1];
    const int* gate = (const int*)d_in[2];
    const int* level = (const int*)d_in[3];
    const float* gcn_w = (const float*)d_in[4];
    const float* gcn_b = (const float*)d_in[5];
    const float* mu_w = (const float*)d_in[6];
    const float* mu_b = (const float*)d_in[7];
    // ls_w/ls_b (8,9) dead (eval mode); af/nf (14..17) dead (level-loop hf never feeds hs;
    // decoder rebuilds hf from hs alone).
    const float* as_w = (const float*)d_in[10];
    const float* as_b = (const float*)d_in[11];
    const float* ns_w = (const float*)d_in[12];
    const float* ns_b = (const float*)d_in[13];
    const float* ua_w = (const float*)d_in[18];
    const float* ua_b = (const float*)d_in[19];
    const float* un_w = (const float*)d_in[20];
    const float* un_b = (const float*)d_in[21];
    const float* dec_ws_w = (const float*)d_in[22];
    const float* dec_wt_w = (const float*)d_in[23];

    const int n = in_sizes[0] / DIM;  // 32768
    const int E = in_sizes[1] / 2;    // 65536
    const int* srcv = ei;
    const int* dstv = ei + E;

    float* hs = (float*)d_out;             // [n, DIM]
    float* hf_out = hs + (size_t)n * DIM;  // [n, DIM]

    char* wp = (char*)d_ws;
    float* x = (float*)wp;      wp += (size_t)n * DIM * 4;      // gcn agg, later zs
    float* x2 = (float*)wp;     wp += (size_t)n * DIM * 4;      // zt
    float* tmpA = (float*)wp;   wp += (size_t)CAP * DIM * 4;    // AND-update staging
    float* tmpN = (float*)wp;   wp += (size_t)CAP * DIM * 4;    // NOT-update staging
    float* uH = (float*)wp;     wp += (size_t)8 * CAP * DIM * 4; // precomputed AND hs-half
    float4* wp4 = (float4*)wp;  wp += (size_t)PACK4_TOTAL * 16; // packed stage weights
    float2* wdec = (float2*)wp; wp += (size_t)DEC_TOTAL * 8;    // packed decoder weights
    float* wprime = (float*)wp; wp += (size_t)DIM * DIM * 4;    // gcn_w @ mu_w
    float* bprime = (float*)wp; wp += (size_t)DIM * 4;          // gcn_b @ mu_w + mu_b
    int4* meta = (int4*)wp;     wp += (size_t)16 * CAP * 16;    // per-class node metadata
    char* small0 = wp;
    int* degi = (int*)wp;   wp += (size_t)n * 4;
    int* cursor = (int*)wp; wp += (size_t)n * 4;
    int* ncnt = (int*)wp;   wp += 16 * 4;
    size_t small_bytes = (size_t)(wp - small0);
    int* bsum = (int*)wp;    wp += 64 * 4;
    int* offs = (int*)wp;    wp += (size_t)(n + 1) * 4;
    int* csr_src = (int*)wp; wp += (size_t)E * 4;
    int* nlist = (int*)wp;   wp += (size_t)16 * n * 4;
    int* clsidx = (int*)wp;  wp += (size_t)n * 4;
    float* dis = (float*)wp; wp += (size_t)n * 4;
    float* inv = (float*)wp; wp += (size_t)n * 4;

    hipMemsetAsync(small0, 0, small_bytes, stream);
    hipMemsetAsync(clsidx, 0xFF, (size_t)n * 4, stream);

    // tiny precompute: W' = gcn_w @ mu_w, packed weights (+ b' tail block)
    mm_kernel<0><<<DIM / 32, 256, 0, stream>>>(gcn_w, mu_w, nullptr, wprime, DIM);
    pack_kernel<<<(PACK4_TOTAL + DEC_TOTAL + 255) / 256 + 1, 256, 0, stream>>>(
        as_w, ua_w, ns_w, un_w, wp4, dec_ws_w, dec_wt_w, wdec, gcn_b, mu_w, mu_b, bprime);

    count_kernel<<<(E + 255) / 256, 256, 0, stream>>>(dstv, degi, E, gate, level,
                                                      nlist, ncnt, clsidx, n);
    scan1_kernel<<<n / 1024, 1024, 0, stream>>>(degi, offs, bsum, dis, inv);
    scan3_kernel<<<n / 1024, 1024, 0, stream>>>(offs, bsum, n);
    csr_fill_kernel<<<(E + 255) / 256, 256, 0, stream>>>(srcv, dstv, offs, cursor, csr_src, E);
    meta_kernel<<<16 * (CAP / 256), 256, 0, stream>>>(nlist, ncnt, offs, meta, n);

    // --- GCN encoder, algebra-folded: hs = agg(hs_init) @ W' + b' ---
    gcn_gather_kernel<<<8192, 256, 0, stream>>>(hs_init, dis, inv, offs, csr_src, x, n);
    mm_kernel<1><<<n / 32, 256, 0, stream>>>(x, wprime, bprime, hs, n);

    // --- uH precompute: hs-half of every AND update (level-invariant) ---
    uh_kernel<<<8 * 64, 256, 0, stream>>>(hs, ua_w, ua_b, nlist, ncnt, uH, n);

    // --- level loop: 2 launches/level (fused commit+gather+update), 1 final commit ---
    for (int l = 1; l <= NLEV; l++) {
        const int cA = l - 1;
        const int cN = NLEV + l - 1;
        const int cNp = NLEV + l - 2;
        if (l == 1)
            and_stage_kernel<false><<<NB_STAGE, 256, 0, stream>>>(
                hs, tmpN, tmpA, meta, csr_src, ncnt, clsidx, wp4,
                as_b, uH, cA, -9, n);
        else
            and_stage_kernel<true><<<NB_STAGE, 256, 0, stream>>>(
                hs, tmpN, tmpA, meta, csr_src, ncnt, clsidx, wp4,
                as_b, uH, cA, cNp, n);
        not_stage_kernel<<<NB_STAGE, 256, 0, stream>>>(
            hs, tmpA, tmpN, meta, csr_src, ncnt, clsidx, wp4,
            ns_b, un_b, cA, cN, n);
    }
    commit_kernel<<<NB_STAGE, 256, 0, stream>>>(hs, tmpN, meta, ncnt, 2 * NLEV - 1, n);

    // --- decoder: zs/zt dense (packed W, depth-2 prefetch), then weighted gather ---
    float* zs = x;
    float* zt = x2;
    mm2_kernel<<<n / 32, 256, 0, stream>>>(hs, wdec, zs, zt, n);
    dec_gather_kernel<<<8192, 256, 0, stream>>>(zs, zt, offs, csr_src, hf_out, n);
}

// Round 24
// 402.729 us; speedup vs baseline: 1.0792x; 1.0792x over previous
//
#include <hip/hip_runtime.h>

#define DIM 128
#define NLEV 8
#define NB_STAGE 512           // stage-kernel grid; 4 waves/block -> 2048 wave-slots
#define NSLOT (NB_STAGE * 4)
#define CAP NSLOT              // max nodes per class (expected ~1213, +24 sigma)

// packed stage-weight offsets (float4 units): slot (k>>1)*64+jl holds
// (W[k][jl], W[k][jl+64], W[k+1][jl], W[k+1][jl+64])
#define AS4 0
#define UA4 4096               // 256 rows -> 8192 float4 (hi half read from L2)
#define NS4 12288
#define UN4 16384
#define PACK4_TOTAL 20480
#define DEC_TOTAL 16384        // float2: (dec_ws[k][j], dec_wt[k][j])

__device__ __forceinline__ int cls_of(int g, int l) {
    if (l < 1 || l > NLEV) return -1;
    if (g == 1) return l - 1;
    if (g == 2) return NLEV + (l - 1);
    return -1;
}

// ---------------- prep kernels ----------------

// fused: deg_count (i<E) + class-list build (blocks covering n)
__global__ __launch_bounds__(256) void count_kernel(const int* __restrict__ dstv,
                                                    int* __restrict__ degi, int E,
                                                    const int* __restrict__ gate,
                                                    const int* __restrict__ level,
                                                    int* __restrict__ nlist,
                                                    int* __restrict__ ncnt,
                                                    int* __restrict__ clsidx, int n) {
    const int i = blockIdx.x * 256 + threadIdx.x;
    if (i < E) atomicAdd(&degi[dstv[i]], 1);
    if ((int)blockIdx.x * 256 < n) {  // block-uniform
        __shared__ int lcnt[16];
        __shared__ int lbase[16];
        const int t = threadIdx.x;
        if (t < 16) lcnt[t] = 0;
        __syncthreads();
        int c = -1, lpos = 0;
        if (i < n) {
            c = cls_of(gate[i], level[i]);
            if (c >= 0) lpos = atomicAdd(&lcnt[c], 1);
        }
        __syncthreads();
        if (t < 16 && lcnt[t] > 0) lbase[t] = atomicAdd(&ncnt[t], lcnt[t]);
        __syncthreads();
        if (c >= 0) {
            int idx = lbase[c] + lpos;
            nlist[c * n + idx] = i;
            clsidx[i] = (c << 16) | idx;
        }
    }
}

// pack stage weights (float4 k-pair layout), decoder weights (float2), b' tail
__global__ void pack_kernel(const float* __restrict__ as_w, const float* __restrict__ ua_w,
                            const float* __restrict__ ns_w, const float* __restrict__ un_w,
                            float4* __restrict__ wp4,
                            const float* __restrict__ ws_w, const float* __restrict__ wt_w,
                            float2* __restrict__ wdec,
                            const float* __restrict__ gcn_b, const float* __restrict__ mu_w,
                            const float* __restrict__ mu_b, float* __restrict__ bp) {
    if (blockIdx.x == gridDim.x - 1) {  // bprime tail block
        const int j = threadIdx.x;
        if (j < DIM) {
            float acc = mu_b[j];
            for (int k = 0; k < DIM; k++) acc = fmaf(gcn_b[k], mu_w[k * DIM + j], acc);
            bp[j] = acc;
        }
        return;
    }
    const int i = blockIdx.x * 256 + threadIdx.x;
    if (i < PACK4_TOTAL) {
        const float* src;
        int local;
        if (i < UA4)      { src = as_w; local = i; }
        else if (i < NS4) { src = ua_w; local = i - UA4; }
        else if (i < UN4) { src = ns_w; local = i - NS4; }
        else              { src = un_w; local = i - UN4; }
        const int kp = local >> 6, jl = local & 63;
        wp4[i] = make_float4(src[(2 * kp) * DIM + jl], src[(2 * kp) * DIM + jl + 64],
                             src[(2 * kp + 1) * DIM + jl], src[(2 * kp + 1) * DIM + jl + 64]);
    } else if (i < PACK4_TOTAL + DEC_TOTAL) {
        const int d = i - PACK4_TOTAL;
        wdec[d] = make_float2(ws_w[d], wt_w[d]);  // d = k*DIM + j
    }
}

// ---- 2-kernel parallel exclusive scan (+ fused deg finalize) ----
__global__ __launch_bounds__(1024) void scan1_kernel(const int* __restrict__ degi,
                                                     int* __restrict__ offs,
                                                     int* __restrict__ bsum,
                                                     float* __restrict__ dis,
                                                     float* __restrict__ inv) {
    __shared__ int sh[1024];
    const int gid = blockIdx.x * 1024 + threadIdx.x;
    const int v = degi[gid];
    {
        float d = (float)v + 1.0f;
        dis[gid] = rsqrtf(d);
        inv[gid] = 1.0f / d;
    }
    sh[threadIdx.x] = v;
    __syncthreads();
    for (int off = 1; off < 1024; off <<= 1) {
        int t = (threadIdx.x >= off) ? sh[threadIdx.x - off] : 0;
        __syncthreads();
        sh[threadIdx.x] += t;
        __syncthreads();
    }
    offs[gid] = sh[threadIdx.x] - v;  // exclusive within block
    if (threadIdx.x == 1023) bsum[blockIdx.x] = sh[1023];
}

// scan3 with local re-scan of bsum (scan2 merged; bsum read-only here)
__global__ __launch_bounds__(1024) void scan3_kernel(int* __restrict__ offs,
                                                     const int* __restrict__ bsum, int n) {
    __shared__ int sbase, stot;
    const int nb = gridDim.x;
    if (threadIdx.x < 64) {
        const int lane = threadIdx.x;
        const int orig = (lane < nb) ? bsum[lane] : 0;
        int v = orig;
#pragma unroll
        for (int off = 1; off < 64; off <<= 1) {
            int t = __shfl_up(v, off, 64);
            if (lane >= off) v += t;
        }
        if (lane == (int)blockIdx.x) sbase = v - orig;  // exclusive base for this block
        if (lane == nb - 1) stot = v;                   // grand total
    }
    __syncthreads();
    const int gid = blockIdx.x * 1024 + threadIdx.x;
    offs[gid] += sbase;
    if (gid == n - 1) offs[n] = stot;
}

__global__ void csr_fill_kernel(const int* __restrict__ srcv, const int* __restrict__ dstv,
                                const int* __restrict__ offs, int* __restrict__ cursor,
                                int* __restrict__ csr_src, int E) {
    int i = blockIdx.x * blockDim.x + threadIdx.x;
    if (i >= E) return;
    int d = dstv[i];
    int pos = offs[d] + atomicAdd(&cursor[d], 1);
    csr_src[pos] = srcv[i];
}

// per-class packed node metadata: meta[c*CAP+idx] = (node, e0, e1, 0)
// collapses the stage kernels' nlist->offs dependent-load chain to ONE int4 load
__global__ __launch_bounds__(256) void meta_kernel(const int* __restrict__ nlist,
                                                   const int* __restrict__ ncnt,
                                                   const int* __restrict__ offs,
                                                   int4* __restrict__ meta, int n) {
    const int c = blockIdx.x >> 3;              // 8 blocks per class (CAP/256)
    const int idx = (blockIdx.x & 7) * 256 + threadIdx.x;
    if (idx >= min(ncnt[c], CAP)) return;
    const int node = nlist[c * n + idx];
    meta[c * CAP + idx] = make_int4(node, offs[node], offs[node + 1], 0);
}

// ---------------- dense matmul: LDS-staged input tile, 32 rows/block ----------------
template <int BIAS>
__global__ __launch_bounds__(256) void mm_kernel(const float* __restrict__ in0,
                                                 const float* __restrict__ W,
                                                 const float* __restrict__ b,
                                                 float* __restrict__ out, int n) {
    const int R = 32;
    __shared__ float tile[R * DIM];
    const size_t row0 = (size_t)blockIdx.x * R;
    for (int t = threadIdx.x; t < R * DIM / 4; t += 256)
        ((float4*)tile)[t] = ((const float4*)(in0 + row0 * DIM))[t];
    __syncthreads();
    const int g = threadIdx.x >> 7;   // row-half 0/1
    const int j = threadIdx.x & 127;  // output column
    float acc[16];
#pragma unroll
    for (int r = 0; r < 16; r++) acc[r] = 0.f;
    const float* tb = tile + (g * 16) * DIM;
    for (int k = 0; k < DIM; k += 4) {
        float w0 = W[(k + 0) * DIM + j];
        float w1 = W[(k + 1) * DIM + j];
        float w2 = W[(k + 2) * DIM + j];
        float w3 = W[(k + 3) * DIM + j];
#pragma unroll
        for (int r = 0; r < 16; r++) {
            const float4 a = *reinterpret_cast<const float4*>(tb + r * DIM + k);
            acc[r] = fmaf(a.x, w0, acc[r]);
            acc[r] = fmaf(a.y, w1, acc[r]);
            acc[r] = fmaf(a.z, w2, acc[r]);
            acc[r] = fmaf(a.w, w3, acc[r]);
        }
    }
    float bias = BIAS ? b[j] : 0.f;
#pragma unroll
    for (int r = 0; r < 16; r++) out[(row0 + g * 16 + r) * DIM + j] = acc[r] + bias;
}

// uH precompute: for all AND classes c in [0,8): uH[c*CAP+idx] = hs[node] @ ua_w[0:128] + ua_b
// (valid because AND-node hs rows hold the encoder value until their own level's commit)
__global__ __launch_bounds__(256) void uh_kernel(const float* __restrict__ hs,
                                                 const float* __restrict__ ua_w,
                                                 const float* __restrict__ ua_b,
                                                 const int* __restrict__ nlist,
                                                 const int* __restrict__ ncnt,
                                                 float* __restrict__ uH, int n) {
    const int c = blockIdx.x >> 6;          // 64 blocks per class, 32 rows each -> CAP rows
    const int i0 = (blockIdx.x & 63) * 32;
    const int cnt = min(ncnt[c], CAP);
    if (i0 >= cnt) return;
    __shared__ float tile[32 * DIM];
    {   // gather-stage 32 node rows (8 threads/row, 4 float4 each)
        const int rt = threadIdx.x >> 3;
        const int ct = threadIdx.x & 7;
        const int idx = min(i0 + rt, cnt - 1);
        const int node = nlist[c * n + idx];
        const float4* s4 = (const float4*)(hs + (size_t)node * DIM);
        float4* d4 = (float4*)(tile + rt * DIM);
#pragma unroll
        for (int i = 0; i < 4; i++) d4[ct + 8 * i] = s4[ct + 8 * i];
    }
    __syncthreads();
    const int g = threadIdx.x >> 7;
    const int j = threadIdx.x & 127;
    float acc[16];
#pragma unroll
    for (int r = 0; r < 16; r++) acc[r] = 0.f;
    const float* tb = tile + (g * 16) * DIM;
    float w0 = ua_w[0 * DIM + j], w1 = ua_w[1 * DIM + j];
    float w2 = ua_w[2 * DIM + j], w3 = ua_w[3 * DIM + j];
    for (int k = 0; k < DIM; k += 4) {
        const int kn = (k + 4 < DIM) ? (k + 4) : 0;
        const float nw0 = ua_w[(kn + 0) * DIM + j];
        const float nw1 = ua_w[(kn + 1) * DIM + j];
        const float nw2 = ua_w[(kn + 2) * DIM + j];
        const float nw3 = ua_w[(kn + 3) * DIM + j];
#pragma unroll
        for (int r = 0; r < 16; r++) {
            const float4 a = *reinterpret_cast<const float4*>(tb + r * DIM + k);
            acc[r] = fmaf(a.x, w0, acc[r]);
            acc[r] = fmaf(a.y, w1, acc[r]);
            acc[r] = fmaf(a.z, w2, acc[r]);
            acc[r] = fmaf(a.w, w3, acc[r]);
        }
        w0 = nw0; w1 = nw1; w2 = nw2; w3 = nw3;
    }
    const float bj = ua_b[j];
#pragma unroll
    for (int r = 0; r < 16; r++) {
        const int idx = i0 + g * 16 + r;
        if (idx < cnt) uH[((size_t)c * CAP + idx) * DIM + j] = acc[r] + bj;
    }
}

// fused decoder matmul: packed (ws,wt) float2 per k, depth-2 prefetch (round-18 proven)
__global__ __launch_bounds__(256) void mm2_kernel(const float* __restrict__ in0,
                                                  const float2* __restrict__ Wd,
                                                  float* __restrict__ zs,
                                                  float* __restrict__ zt, int n) {
    const int R = 32;
    __shared__ float tile[R * DIM];
    const size_t row0 = (size_t)blockIdx.x * R;
    for (int t = threadIdx.x; t < R * DIM / 4; t += 256)
        ((float4*)tile)[t] = ((const float4*)(in0 + row0 * DIM))[t];
    __syncthreads();
    const int g = threadIdx.x >> 7;
    const int j = threadIdx.x & 127;
    float accs[16], acct[16];
#pragma unroll
    for (int r = 0; r < 16; r++) { accs[r] = 0.f; acct[r] = 0.f; }
    const float* tb = tile + (g * 16) * DIM;
    float2 s0 = Wd[0 * DIM + j], s1 = Wd[1 * DIM + j];
    float2 s2 = Wd[2 * DIM + j], s3 = Wd[3 * DIM + j];
    for (int k = 0; k < DIM; k += 2) {
        const int kn = (k + 4 < DIM) ? (k + 4) : 0;  // depth-2 prefetch
        const float2 p0 = Wd[(kn + 0) * DIM + j];
        const float2 p1 = Wd[(kn + 1) * DIM + j];
#pragma unroll
        for (int r = 0; r < 16; r++) {
            const float2 a = *reinterpret_cast<const float2*>(tb + r * DIM + k);
            accs[r] = fmaf(a.x, s0.x, accs[r]);
            acct[r] = fmaf(a.x, s0.y, acct[r]);
            accs[r] = fmaf(a.y, s1.x, accs[r]);
            acct[r] = fmaf(a.y, s1.y, acct[r]);
        }
        s0 = s2; s1 = s3; s2 = p0; s3 = p1;
    }
#pragma unroll
    for (int r = 0; r < 16; r++) {
        zs[(row0 + g * 16 + r) * DIM + j] = accs[r];
        zt[(row0 + g * 16 + r) * DIM + j] = acct[r];
    }
}

// ---------------- GCN aggregate as gather (bias folded into b'; 2-edge unroll) ----------------
__global__ __launch_bounds__(256) void gcn_gather_kernel(const float* __restrict__ x,
                                                         const float* __restrict__ dis,
                                                         const float* __restrict__ inv,
                                                         const int* __restrict__ offs,
                                                         const int* __restrict__ csr_src,
                                                         float* __restrict__ y, int n) {
    int slot = threadIdx.x >> 7, j = threadIdx.x & 127;
    for (int node = blockIdx.x * 2 + slot; node < n; node += gridDim.x * 2) {
        float dn = dis[node];
        float acc = inv[node] * x[(size_t)node * DIM + j];
        const int p0 = offs[node], p1 = offs[node + 1];
        for (int p = p0; p < p1; p += 2) {
            const bool two = (p + 1 < p1);
            const int s0 = csr_src[p];
            const int s1 = two ? csr_src[p + 1] : s0;
            const float c0 = dn * dis[s0];
            const float c1 = dn * dis[s1];
            const float v0 = x[(size_t)s0 * DIM + j];
            const float v1 = x[(size_t)s1 * DIM + j];
            acc = fmaf(c0, v0, acc);
            if (two) acc = fmaf(c1, v1, acc);
        }
        y[(size_t)node * DIM + j] = acc;
    }
}

// ---------------- level-stage kernels: wave-per-node, float4-packed LDS W ----------------

// copy a packed 64KB W (4096 float4) into LDS, fully coalesced
__device__ __forceinline__ void stage_pk(const float4* __restrict__ Wp, float4* __restrict__ W2) {
    for (int t = threadIdx.x; t < 4096; t += 256) W2[t] = Wp[t];
}

template <bool MERGE>
__device__ __forceinline__ const float* resolve_row(const float* __restrict__ base,
                                                    const float* __restrict__ tmp,
                                                    const int* __restrict__ clsidx,
                                                    int mcls, int s) {
    if (MERGE) {
        int cc = clsidx[s];
        if ((cc >> 16) == mcls && (cc & 0xFFFF) < CAP) return tmp + (size_t)(cc & 0xFFFF) * DIM;
    }
    return base + (size_t)s * DIM;
}

// load one edge pair's src rows into registers (global; issued early for latency hiding)
template <bool MERGE>
__device__ __forceinline__ void load_pair(const float* __restrict__ hs,
                                          const float* __restrict__ tmp,
                                          const int* __restrict__ clsidx, int mcls,
                                          const int* __restrict__ csr_src,
                                          int p, int e1, int lane,
                                          float& a00, float& a01, float& a10, float& a11) {
    const int s0 = csr_src[p];
    const int s1 = (p + 1 < e1) ? csr_src[p + 1] : s0;
    const float* r0 = resolve_row<MERGE>(hs, tmp, clsidx, mcls, s0);
    const float* r1 = resolve_row<MERGE>(hs, tmp, clsidx, mcls, s1);
    a00 = r0[lane]; a01 = r0[lane + 64];
    a10 = r1[lane]; a11 = r1[lane + 64];
}

// 128-step matvec col-pair accumulation from per-wave LDS row `ar`, W read directly
// from L2 (fully coalesced float4 per lane; single pass -> latency amortized, no staging)
__device__ __forceinline__ void mv128_l2(const float* __restrict__ ar,
                                         const float4* __restrict__ Wg,
                                         int lane, float& o0, float& o1) {
#pragma unroll 8
    for (int k = 0; k < 128; k += 4) {
        const float4 a = *(const float4*)&ar[k];  // uniform-address LDS broadcast
        const float4 wA = Wg[(k >> 1) * 64 + lane];        // rows k, k+1
        const float4 wB = Wg[((k >> 1) + 1) * 64 + lane];  // rows k+2, k+3
        o0 = fmaf(a.x, wA.x, o0); o1 = fmaf(a.x, wA.y, o1);
        o0 = fmaf(a.y, wA.z, o0); o1 = fmaf(a.y, wA.w, o1);
        o0 = fmaf(a.z, wB.x, o0); o1 = fmaf(a.z, wB.y, o1);
        o0 = fmaf(a.w, wB.z, o0); o1 = fmaf(a.w, wB.w, o1);
    }
}

// AND stage: commit tmpN(cNp)->hs ; agg = gather(as_w LDS, merged w/ tmpN) ;
//            tmpA[idx] = relu( uH[idx] + agg @ ua_w[128:256] (L2) )
template <bool MERGE>
__global__ __launch_bounds__(256) void and_stage_kernel(
        float* __restrict__ hs, const float* __restrict__ tmpN, float* __restrict__ tmpA,
        const int4* __restrict__ meta, const int* __restrict__ csr_src,
        const int* __restrict__ nlist, const int* __restrict__ ncnt,
        const int* __restrict__ clsidx, const float4* __restrict__ wp4,
        const float* __restrict__ as_b, const float* __restrict__ uH,
        int cA, int cNp, int n) {
    const int cnt = min(ncnt[cA], CAP);
    const int cntp = MERGE ? min(ncnt[cNp], CAP) : 0;
    const int lim = max(cnt, cntp);
    if ((int)blockIdx.x * 4 >= lim) return;  // block-uniform early exit
    __shared__ float4 W2[4096];
    __shared__ float arow[4][256];  // per-wave row scratch (2 rows of 128)
    const int lane = threadIdx.x & 63;
    const int wv = threadIdx.x >> 6;
    const int gslot = (blockIdx.x << 2) | wv;

    // ---- early global loads (hide under W staging) ----
    const bool act = gslot < cnt;
    const int4 mt = act ? meta[cA * CAP + gslot] : make_int4(0, 0, 0, 0);
    const int e0 = mt.y, e1 = mt.z;
    float u0 = 0.f, u1 = 0.f;
    if (act) {  // precomputed hs-half of update (includes ua_b)
        u0 = uH[((size_t)cA * CAP + gslot) * DIM + lane];
        u1 = uH[((size_t)cA * CAP + gslot) * DIM + lane + 64];
    }
    float pa0 = 0.f, pa1 = 0.f, pa2 = 0.f, pa3 = 0.f;
    if (act && e0 < e1)
        load_pair<MERGE>(hs, tmpN, clsidx, cNp, csr_src, e0, e1, lane, pa0, pa1, pa2, pa3);
    // commit previous level's NOT updates (gathers read those rows via tmpN indirection)
    if (MERGE) {
        for (int idx = gslot; idx < cntp; idx += NSLOT) {
            const int node = nlist[cNp * n + idx];
            hs[(size_t)node * DIM + lane] = tmpN[(size_t)idx * DIM + lane];
            hs[(size_t)node * DIM + lane + 64] = tmpN[(size_t)idx * DIM + lane + 64];
        }
    }
    stage_pk(wp4 + AS4, W2);
    __syncthreads();

    // ---- gather: software-pipelined edge pairs, LDS row-broadcast matvec ----
    const float bj_as0 = as_b[lane], bj_as1 = as_b[lane + 64];
    float ag0 = 0.f, ag1 = 0.f;
    if (act) {
        float* ar = arow[wv];
        float a00 = pa0, a01 = pa1, a10 = pa2, a11 = pa3;
        for (int p = e0; p < e1; p += 2) {
            ar[lane] = a00; ar[64 + lane] = a01;
            ar[128 + lane] = a10; ar[192 + lane] = a11;
            const bool two = (p + 1 < e1);
            float n00 = 0.f, n01 = 0.f, n10 = 0.f, n11 = 0.f;
            if (p + 2 < e1)  // prefetch next pair during this pair's k-loop
                load_pair<MERGE>(hs, tmpN, clsidx, cNp, csr_src, p + 2, e1, lane,
                                 n00, n01, n10, n11);
            float m00 = bj_as0, m01 = bj_as1, m10 = bj_as0, m11 = bj_as1;
#pragma unroll 8
            for (int k = 0; k < 128; k += 4) {
                const float4 a0 = *(const float4*)&ar[k];
                const float4 a1 = *(const float4*)&ar[128 + k];
                const float4 wA = W2[(k >> 1) * 64 + lane];
                const float4 wB = W2[((k >> 1) + 1) * 64 + lane];
                m00 = fmaf(a0.x, wA.x, m00); m01 = fmaf(a0.x, wA.y, m01);
                m10 = fmaf(a1.x, wA.x, m10); m11 = fmaf(a1.x, wA.y, m11);
                m00 = fmaf(a0.y, wA.z, m00); m01 = fmaf(a0.y, wA.w, m01);
                m10 = fmaf(a1.y, wA.z, m10); m11 = fmaf(a1.y, wA.w, m11);
                m00 = fmaf(a0.z, wB.x, m00); m01 = fmaf(a0.z, wB.y, m01);
                m10 = fmaf(a1.z, wB.x, m10); m11 = fmaf(a1.z, wB.y, m11);
                m00 = fmaf(a0.w, wB.z, m00); m01 = fmaf(a0.w, wB.w, m01);
                m10 = fmaf(a1.w, wB.z, m10); m11 = fmaf(a1.w, wB.w, m11);
            }
            ag0 += fmaxf(m00, 0.f);
            ag1 += fmaxf(m01, 0.f);
            if (two) { ag0 += fmaxf(m10, 0.f); ag1 += fmaxf(m11, 0.f); }
            a00 = n00; a01 = n01; a10 = n10; a11 = n11;
        }
    }

    // ---- update: u = uH + agg @ ua_w[128:256] read from L2; no staging, no barrier ----
    if (act) {
        float* ar = arow[wv];   // per-wave scratch: wave-synchronous, no barrier needed
        ar[lane] = ag0; ar[64 + lane] = ag1;
        mv128_l2(ar, wp4 + UA4 + 4096, lane, u0, u1);
        tmpA[(size_t)gslot * DIM + lane] = fmaxf(u0, 0.f);
        tmpA[(size_t)gslot * DIM + lane + 64] = fmaxf(u1, 0.f);
    }
}

// NOT stage: commit tmpA(cA)->hs ; agg = gather(ns_w LDS, merged w/ tmpA) ;
//            tmpN[idx] = tanh( agg @ un_w (L2) + un_b )
__global__ __launch_bounds__(256) void not_stage_kernel(
        float* __restrict__ hs, const float* __restrict__ tmpA, float* __restrict__ tmpN,
        const int4* __restrict__ meta, const int* __restrict__ csr_src,
        const int* __restrict__ nlist, const int* __restrict__ ncnt,
        const int* __restrict__ clsidx, const float4* __restrict__ wp4,
        const float* __restrict__ ns_b, const float* __restrict__ un_b,
        int cA, int cN, int n) {
    const int cnt = min(ncnt[cN], CAP);
    const int cntA = min(ncnt[cA], CAP);
    const int lim = max(cnt, cntA);
    if ((int)blockIdx.x * 4 >= lim) return;
    __shared__ float4 W2[4096];
    __shared__ float arow[4][256];
    const int lane = threadIdx.x & 63;
    const int wv = threadIdx.x >> 6;
    const int gslot = (blockIdx.x << 2) | wv;

    const bool act = gslot < cnt;
    const int4 mt = act ? meta[cN * CAP + gslot] : make_int4(0, 0, 0, 0);
    const int e0 = mt.y, e1 = mt.z;
    float pa0 = 0.f, pa1 = 0.f, pa2 = 0.f, pa3 = 0.f;
    if (act && e0 < e1)
        load_pair<true>(hs, tmpA, clsidx, cA, csr_src, e0, e1, lane, pa0, pa1, pa2, pa3);
    // commit this level's AND updates
    for (int idx = gslot; idx < cntA; idx += NSLOT) {
        const int node = nlist[cA * n + idx];
        hs[(size_t)node * DIM + lane] = tmpA[(size_t)idx * DIM + lane];
        hs[(size_t)node * DIM + lane + 64] = tmpA[(size_t)idx * DIM + lane + 64];
    }
    stage_pk(wp4 + NS4, W2);
    __syncthreads();

    const float bj_ns0 = ns_b[lane], bj_ns1 = ns_b[lane + 64];
    float ag0 = 0.f, ag1 = 0.f;
    if (act) {
        float* ar = arow[wv];
        float a00 = pa0, a01 = pa1, a10 = pa2, a11 = pa3;
        for (int p = e0; p < e1; p += 2) {
            ar[lane] = a00; ar[64 + lane] = a01;
            ar[128 + lane] = a10; ar[192 + lane] = a11;
            const bool two = (p + 1 < e1);
            float n00 = 0.f, n01 = 0.f, n10 = 0.f, n11 = 0.f;
            if (p + 2 < e1)
                load_pair<true>(hs, tmpA, clsidx, cA, csr_src, p + 2, e1, lane,
                                n00, n01, n10, n11);
            float m00 = bj_ns0, m01 = bj_ns1, m10 = bj_ns0, m11 = bj_ns1;
#pragma unroll 8
            for (int k = 0; k < 128; k += 4) {
                const float4 a0 = *(const float4*)&ar[k];
                const float4 a1 = *(const float4*)&ar[128 + k];
                const float4 wA = W2[(k >> 1) * 64 + lane];
                const float4 wB = W2[((k >> 1) + 1) * 64 + lane];
                m00 = fmaf(a0.x, wA.x, m00); m01 = fmaf(a0.x, wA.y, m01);
                m10 = fmaf(a1.x, wA.x, m10); m11 = fmaf(a1.x, wA.y, m11);
                m00 = fmaf(a0.y, wA.z, m00); m01 = fmaf(a0.y, wA.w, m01);
                m10 = fmaf(a1.y, wA.z, m10); m11 = fmaf(a1.y, wA.w, m11);
                m00 = fmaf(a0.z, wB.x, m00); m01 = fmaf(a0.z, wB.y, m01);
                m10 = fmaf(a1.z, wB.x, m10); m11 = fmaf(a1.z, wB.y, m11);
                m00 = fmaf(a0.w, wB.z, m00); m01 = fmaf(a0.w, wB.w, m01);
                m10 = fmaf(a1.w, wB.z, m10); m11 = fmaf(a1.w, wB.w, m11);
            }
            ag0 += fmaxf(m00, 0.f);
            ag1 += fmaxf(m01, 0.f);
            if (two) { ag0 += fmaxf(m10, 0.f); ag1 += fmaxf(m11, 0.f); }
            a00 = n00; a01 = n01; a10 = n10; a11 = n11;
        }
    }

    // ---- update from L2 W; no staging, no barriers ----
    if (act) {
        float u0 = un_b[lane], u1 = un_b[lane + 64];
        float* ar = arow[wv];
        ar[lane] = ag0; ar[64 + lane] = ag1;
        mv128_l2(ar, wp4 + UN4, lane, u0, u1);
        tmpN[(size_t)gslot * DIM + lane] = tanhf(u0);
        tmpN[(size_t)gslot * DIM + lane + 64] = tanhf(u1);
    }
}

// final commit of last level's tmpN -> hs
__global__ __launch_bounds__(256) void commit_kernel(float* __restrict__ hs,
                                                     const float* __restrict__ tmp,
                                                     const int4* __restrict__ meta,
                                                     const int* __restrict__ ncnt,
                                                     int c, int n) {
    const int lane = threadIdx.x & 63;
    const int gslot = (blockIdx.x << 2) | (threadIdx.x >> 6);
    const int cnt = min(ncnt[c], CAP);
    for (int idx = gslot; idx < cnt; idx += NSLOT) {
        const int node = meta[c * CAP + idx].x;
        hs[(size_t)node * DIM + lane] = tmp[(size_t)idx * DIM + lane];
        hs[(size_t)node * DIM + lane + 64] = tmp[(size_t)idx * DIM + lane + 64];
    }
}

// ---------------- decoder as gather (wave per node, 2-edge unroll) ----------------
__global__ __launch_bounds__(256) void dec_gather_kernel(const float* __restrict__ zs,
                                                         const float* __restrict__ zt,
                                                         const int* __restrict__ offs,
                                                         const int* __restrict__ csr_src,
                                                         float* __restrict__ hf_out, int n) {
    int w = threadIdx.x >> 6, lane = threadIdx.x & 63;
    for (int node = blockIdx.x * 4 + w; node < n; node += gridDim.x * 4) {
        float b0 = zt[(size_t)node * DIM + lane];
        float b1 = zt[(size_t)node * DIM + 64 + lane];
        float acc0 = 0.f, acc1 = 0.f;
        const int p0 = offs[node], p1 = offs[node + 1];
        for (int p = p0; p < p1; p += 2) {
            const bool two = (p + 1 < p1);
            const int s0 = csr_src[p];
            const int s1 = two ? csr_src[p + 1] : s0;
            const float a00 = zs[(size_t)s0 * DIM + lane];
            const float a01 = zs[(size_t)s0 * DIM + 64 + lane];
            const float a10 = zs[(size_t)s1 * DIM + lane];
            const float a11 = zs[(size_t)s1 * DIM + 64 + lane];
            float pd0 = a00 * b0 + a01 * b1;
            float pd1 = a10 * b0 + a11 * b1;
#pragma unroll
            for (int off = 32; off > 0; off >>= 1) {
                pd0 += __shfl_xor(pd0, off, 64);
                pd1 += __shfl_xor(pd1, off, 64);
            }
            const float w0 = 1.f / (1.f + __expf(-pd0));
            acc0 = fmaf(w0, a00, acc0);
            acc1 = fmaf(w0, a01, acc1);
            if (two) {
                const float w1 = 1.f / (1.f + __expf(-pd1));
                acc0 = fmaf(w1, a10, acc0);
                acc1 = fmaf(w1, a11, acc1);
            }
        }
        hf_out[(size_t)node * DIM + lane] = acc0;
        hf_out[(size_t)node * DIM + 64 + lane] = acc1;
    }
}

extern "C" void kernel_launch(void* const* d_in, const int* in_sizes, int n_in,
                              void* d_out, int out_size, void* d_ws, size_t ws_size,
                              hipStream_t stream) {
    const float* hs_init = (const float*)d_in[0];
    const int* ei = (const int*)d_in[1];
    const int* gate = (const int*)d_in[2];
    const int* level = (const int*)d_in[3];
    const float* gcn_w = (const float*)d_in[4];
    const float* gcn_b = (const float*)d_in[5];
    const float* mu_w = (const float*)d_in[6];
    const float* mu_b = (const float*)d_in[7];
    // ls_w/ls_b (8,9) dead (eval mode); af/nf (14..17) dead (level-loop hf never feeds hs;
    // decoder rebuilds hf from hs alone).
    const float* as_w = (const float*)d_in[10];
    const float* as_b = (const float*)d_in[11];
    const float* ns_w = (const float*)d_in[12];
    const float* ns_b = (const float*)d_in[13];
    const float* ua_w = (const float*)d_in[18];
    const float* ua_b = (const float*)d_in[19];
    const float* un_w = (const float*)d_in[20];
    const float* un_b = (const float*)d_in[21];
    const float* dec_ws_w = (const float*)d_in[22];
    const float* dec_wt_w = (const float*)d_in[23];

    const int n = in_sizes[0] / DIM;  // 32768
    const int E = in_sizes[1] / 2;    // 65536
    const int* srcv = ei;
    const int* dstv = ei + E;

    float* hs = (float*)d_out;             // [n, DIM]
    float* hf_out = hs + (size_t)n * DIM;  // [n, DIM]

    char* wp = (char*)d_ws;
    float* x = (float*)wp;      wp += (size_t)n * DIM * 4;      // gcn agg, later zs
    float* x2 = (float*)wp;     wp += (size_t)n * DIM * 4;      // zt
    float* tmpA = (float*)wp;   wp += (size_t)CAP * DIM * 4;    // AND-update staging
    float* tmpN = (float*)wp;   wp += (size_t)CAP * DIM * 4;    // NOT-update staging
    float* uH = (float*)wp;     wp += (size_t)8 * CAP * DIM * 4; // precomputed AND hs-half
    float4* wp4 = (float4*)wp;  wp += (size_t)PACK4_TOTAL * 16; // packed stage weights
    float2* wdec = (float2*)wp; wp += (size_t)DEC_TOTAL * 8;    // packed decoder weights
    float* wprime = (float*)wp; wp += (size_t)DIM * DIM * 4;    // gcn_w @ mu_w
    float* bprime = (float*)wp; wp += (size_t)DIM * 4;          // gcn_b @ mu_w + mu_b
    int4* meta = (int4*)wp;     wp += (size_t)16 * CAP * 16;    // per-class node metadata
    char* small0 = wp;
    int* degi = (int*)wp;   wp += (size_t)n * 4;
    int* cursor = (int*)wp; wp += (size_t)n * 4;
    int* ncnt = (int*)wp;   wp += 16 * 4;
    size_t small_bytes = (size_t)(wp - small0);
    int* bsum = (int*)wp;    wp += 64 * 4;
    int* offs = (int*)wp;    wp += (size_t)(n + 1) * 4;
    int* csr_src = (int*)wp; wp += (size_t)E * 4;
    int* nlist = (int*)wp;   wp += (size_t)16 * n * 4;
    int* clsidx = (int*)wp;  wp += (size_t)n * 4;
    float* dis = (float*)wp; wp += (size_t)n * 4;
    float* inv = (float*)wp; wp += (size_t)n * 4;

    hipMemsetAsync(small0, 0, small_bytes, stream);
    hipMemsetAsync(clsidx, 0xFF, (size_t)n * 4, stream);

    // tiny precompute: W' = gcn_w @ mu_w, packed weights (+ b' tail block)
    mm_kernel<0><<<DIM / 32, 256, 0, stream>>>(gcn_w, mu_w, nullptr, wprime, DIM);
    pack_kernel<<<(PACK4_TOTAL + DEC_TOTAL + 255) / 256 + 1, 256, 0, stream>>>(
        as_w, ua_w, ns_w, un_w, wp4, dec_ws_w, dec_wt_w, wdec, gcn_b, mu_w, mu_b, bprime);

    count_kernel<<<(E + 255) / 256, 256, 0, stream>>>(dstv, degi, E, gate, level,
                                                      nlist, ncnt, clsidx, n);
    scan1_kernel<<<n / 1024, 1024, 0, stream>>>(degi, offs, bsum, dis, inv);
    scan3_kernel<<<n / 1024, 1024, 0, stream>>>(offs, bsum, n);
    csr_fill_kernel<<<(E + 255) / 256, 256, 0, stream>>>(srcv, dstv, offs, cursor, csr_src, E);
    meta_kernel<<<16 * (CAP / 256), 256, 0, stream>>>(nlist, ncnt, offs, meta, n);

    // --- GCN encoder, algebra-folded: hs = agg(hs_init) @ W' + b' ---
    gcn_gather_kernel<<<8192, 256, 0, stream>>>(hs_init, dis, inv, offs, csr_src, x, n);
    mm_kernel<1><<<n / 32, 256, 0, stream>>>(x, wprime, bprime, hs, n);

    // --- uH precompute: hs-half of every AND update (level-invariant) ---
    uh_kernel<<<8 * 64, 256, 0, stream>>>(hs, ua_w, ua_b, nlist, ncnt, uH, n);

    // --- level loop: 2 launches/level (fused commit+gather+update), 1 final commit ---
    for (int l = 1; l <= NLEV; l++) {
        const int cA = l - 1;
        const int cN = NLEV + l - 1;
        const int cNp = NLEV + l - 2;
        if (l == 1)
            and_stage_kernel<false><<<NB_STAGE, 256, 0, stream>>>(
                hs, tmpN, tmpA, meta, csr_src, nlist, ncnt, clsidx, wp4,
                as_b, uH, cA, -9, n);
        else
            and_stage_kernel<true><<<NB_STAGE, 256, 0, stream>>>(
                hs, tmpN, tmpA, meta, csr_src, nlist, ncnt, clsidx, wp4,
                as_b, uH, cA, cNp, n);
        not_stage_kernel<<<NB_STAGE, 256, 0, stream>>>(
            hs, tmpA, tmpN, meta, csr_src, nlist, ncnt, clsidx, wp4,
            ns_b, un_b, cA, cN, n);
    }
    commit_kernel<<<NB_STAGE, 256, 0, stream>>>(hs, tmpN, meta, ncnt, 2 * NLEV - 1, n);

    // --- decoder: zs/zt dense (packed W, depth-2 prefetch), then weighted gather ---
    float* zs = x;
    float* zt = x2;
    mm2_kernel<<<n / 32, 256, 0, stream>>>(hs, wdec, zs, zt, n);
    dec_gather_kernel<<<8192, 256, 0, stream>>>(zs, zt, offs, csr_src, hf_out, n);
}